// Round 1
// baseline (769.840 us; speedup 1.0000x reference)
//
#include <hip/hip_runtime.h>
#include <hip/hip_bf16.h>
#include <hip/hip_fp16.h>

// KAN layer as one fp16 MFMA GEMM with 9x expanded K.
// out[b,o] = sum_i x[b,i]*bw[o,i] + 0.1 * sum_{i,g} sw[o,i,g]*relu(x[b,i]-kn[g])
//          = sum_k Feat[b,k] * Wm[o,k],  k = i*9 + c, c=0 -> base, c=1..8 -> spline g
#define BATCH 4096
#define IN_F  2048
#define OUT_F 2048
#define KDIM  (IN_F * 9)   // 18432, divisible by 64

typedef __attribute__((ext_vector_type(8))) _Float16 f16x8;
typedef __attribute__((ext_vector_type(4))) float    f32x4;

// ---------------- prep: merged weights, fp16, K-major [o][i*9+c] ----------------
__global__ __launch_bounds__(256) void prep_W(const float* __restrict__ bw,
                                              const float* __restrict__ sw,
                                              _Float16* __restrict__ W) {
  int idx = blockIdx.x * 256 + threadIdx.x;        // flat (o,i), exact grid
  _Float16* dst = W + (size_t)idx * 9;
  dst[0] = (_Float16)bw[idx];
  const float4* s = (const float4*)(sw + (size_t)idx * 8);  // 32B aligned, contiguous
  float4 s0 = s[0], s1 = s[1];
  dst[1] = (_Float16)(0.1f * s0.x);
  dst[2] = (_Float16)(0.1f * s0.y);
  dst[3] = (_Float16)(0.1f * s0.z);
  dst[4] = (_Float16)(0.1f * s0.w);
  dst[5] = (_Float16)(0.1f * s1.x);
  dst[6] = (_Float16)(0.1f * s1.y);
  dst[7] = (_Float16)(0.1f * s1.z);
  dst[8] = (_Float16)(0.1f * s1.w);
}

// ---------------- prep: features, fp16, K-major [b][i*9+c] ----------------
__global__ __launch_bounds__(256) void prep_A(const float* __restrict__ x,
                                              const float* __restrict__ kn,
                                              _Float16* __restrict__ A) {
  int idx = blockIdx.x * 256 + threadIdx.x;        // flat (b,i), exact grid
  float v = x[idx];
  _Float16* dst = A + (size_t)idx * 9;
  dst[0] = (_Float16)v;
#pragma unroll
  for (int g = 0; g < 8; ++g) {
    float r = v - kn[g];
    dst[1 + g] = (_Float16)(r > 0.f ? r : 0.f);
  }
}

// ---------------- GEMM: C[M,N] = A[M,K] @ W[N,K]^T, fp16 in / fp32 out ----------------
#define BM 128
#define BN 128
#define BK 64

__global__ __launch_bounds__(256) void gemm_bt(const _Float16* __restrict__ A,
                                               const _Float16* __restrict__ W,
                                               float* __restrict__ C) {
  constexpr int M = BATCH, N = OUT_F, K = KDIM;
  __shared__ _Float16 As[BM * BK];   // 16 KB, row-major, K contiguous
  __shared__ _Float16 Bs[BN * BK];   // 16 KB

  const int tid  = threadIdx.x;
  const int lane = tid & 63;
  const int wv   = tid >> 6;          // 0..3
  const int wm   = wv >> 1;           // wave row-half
  const int wn   = wv & 1;            // wave col-half
  const int m0   = blockIdx.y * BM;
  const int n0   = blockIdx.x * BN;

  f32x4 acc[4][4] = {};

  // staging geometry: 256 thr x 16B = 32 rows/pass, 4 passes for 128 rows.
  // LDS dest = wave-uniform base + lane*16  (required by global_load_lds)
  const int rowS = tid >> 3;          // 0..31
  const int kgS  = (tid & 7) * 8;     // fp16 offset in row

  for (int k0 = 0; k0 < K; k0 += BK) {
#pragma unroll
    for (int p = 0; p < 4; ++p) {
      const int r = p * 32 + rowS;
      const _Float16* ga = A + (size_t)(m0 + r) * K + k0 + kgS;
      const _Float16* gw = W + (size_t)(n0 + r) * K + k0 + kgS;
      __builtin_amdgcn_global_load_lds(
          (const __attribute__((address_space(1))) void*)ga,
          (__attribute__((address_space(3))) void*)(As + r * BK + kgS), 16, 0, 0);
      __builtin_amdgcn_global_load_lds(
          (const __attribute__((address_space(1))) void*)gw,
          (__attribute__((address_space(3))) void*)(Bs + r * BK + kgS), 16, 0, 0);
    }
    __syncthreads();

#pragma unroll
    for (int kk = 0; kk < BK; kk += 32) {
      const int koff = kk + ((lane >> 4) << 3);   // quad*8 within 32-K slab
      f16x8 af[4], bfr[4];
#pragma unroll
      for (int mi = 0; mi < 4; ++mi) {
        const int r = wm * 64 + mi * 16 + (lane & 15);
        af[mi] = *(const f16x8*)(As + r * BK + koff);   // ds_read_b128
      }
#pragma unroll
      for (int ni = 0; ni < 4; ++ni) {
        const int r = wn * 64 + ni * 16 + (lane & 15);
        bfr[ni] = *(const f16x8*)(Bs + r * BK + koff);
      }
#pragma unroll
      for (int mi = 0; mi < 4; ++mi)
#pragma unroll
        for (int ni = 0; ni < 4; ++ni)
          acc[mi][ni] = __builtin_amdgcn_mfma_f32_16x16x32_f16(af[mi], bfr[ni],
                                                               acc[mi][ni], 0, 0, 0);
    }
    __syncthreads();
  }

  // epilogue: C/D layout col=lane&15, row=(lane>>4)*4+reg  [dtype-independent, m89/m121]
  const int cn = lane & 15;
  const int r4 = (lane >> 4) * 4;
#pragma unroll
  for (int mi = 0; mi < 4; ++mi) {
    const int rowb = m0 + wm * 64 + mi * 16 + r4;
#pragma unroll
    for (int ni = 0; ni < 4; ++ni) {
      const int col = n0 + wn * 64 + ni * 16 + cn;
#pragma unroll
      for (int reg = 0; reg < 4; ++reg)
        C[(size_t)(rowb + reg) * N + col] = acc[mi][ni][reg];
    }
  }
}

// ---------------- fallback (only if ws too small): fp32, wave per (b,o) ----------------
__global__ __launch_bounds__(256) void kan_naive(const float* __restrict__ x,
                                                 const float* __restrict__ bw,
                                                 const float* __restrict__ sw,
                                                 const float* __restrict__ kn,
                                                 float* __restrict__ out) {
  const int lane = threadIdx.x & 63;
  const int o = blockIdx.x * 4 + (threadIdx.x >> 6);
  const int b = blockIdx.y;
  float k[8];
#pragma unroll
  for (int g = 0; g < 8; ++g) k[g] = kn[g];
  float acc = 0.f;
  for (int i = lane; i < IN_F; i += 64) {
    const float v = x[(size_t)b * IN_F + i];
    float sp = 0.f;
    const float* s = sw + ((size_t)o * IN_F + i) * 8;
#pragma unroll
    for (int g = 0; g < 8; ++g) {
      float r = v - k[g];
      sp += s[g] * (r > 0.f ? r : 0.f);
    }
    acc += v * bw[(size_t)o * IN_F + i] + 0.1f * sp;
  }
#pragma unroll
  for (int off = 32; off; off >>= 1) acc += __shfl_down(acc, off, 64);
  if (lane == 0) out[(size_t)b * OUT_F + o] = acc;
}

extern "C" void kernel_launch(void* const* d_in, const int* in_sizes, int n_in,
                              void* d_out, int out_size, void* d_ws, size_t ws_size,
                              hipStream_t stream) {
  const float* x  = (const float*)d_in[0];
  const float* bw = (const float*)d_in[1];
  const float* sw = (const float*)d_in[2];
  const float* kn = (const float*)d_in[3];
  float* out = (float*)d_out;

  const size_t wbytes = (size_t)OUT_F * KDIM * sizeof(_Float16);   // 72 MB
  const size_t abytes = (size_t)BATCH * KDIM * sizeof(_Float16);   // 144 MB

  if (ws_size >= wbytes + abytes) {
    _Float16* W = (_Float16*)d_ws;
    _Float16* A = (_Float16*)((char*)d_ws + wbytes);
    prep_W<<<(OUT_F * IN_F) / 256, 256, 0, stream>>>(bw, sw, W);
    prep_A<<<(BATCH * IN_F) / 256, 256, 0, stream>>>(x, kn, A);
    dim3 grid(OUT_F / BN, BATCH / BM);   // (16, 32) = 512 blocks
    gemm_bt<<<grid, 256, 0, stream>>>(A, W, out);
  } else {
    dim3 grid(OUT_F / 4, BATCH);
    kan_naive<<<grid, 256, 0, stream>>>(x, bw, sw, kn, out);
  }
}

// Round 2
// 734.011 us; speedup vs baseline: 1.0488x; 1.0488x over previous
//
#include <hip/hip_runtime.h>
#include <hip/hip_bf16.h>
#include <hip/hip_fp16.h>

// KAN layer as one fp16 MFMA GEMM with 9x expanded K (k = i*9 + c).
// R2: XOR-swizzled LDS (kills 16-way bank conflicts), split-K=4 (occupancy
// 2->5 blocks/CU), LDS-staged vectorized prep kernels.
#define BATCH 4096
#define IN_F  2048
#define OUT_F 2048
#define KDIM  (IN_F * 9)   // 18432
#define MN    ((size_t)BATCH * OUT_F)

typedef __attribute__((ext_vector_type(8))) _Float16 f16x8;
typedef __attribute__((ext_vector_type(4))) float    f32x4;

// ---------------- prep: merged weights, fp16, K-major [o][i*9+c] ----------------
__global__ __launch_bounds__(256) void prep_W(const float* __restrict__ bw,
                                              const float* __restrict__ sw,
                                              _Float16* __restrict__ W) {
  __shared__ _Float16 buf[2048 * 9];
  const int t = threadIdx.x;
  const size_t base = (size_t)blockIdx.x * 2048;

  float b[8];
  const float4* bv = (const float4*)(bw + base + t * 8);
  float4 b0 = bv[0], b1 = bv[1];
  b[0]=b0.x; b[1]=b0.y; b[2]=b0.z; b[3]=b0.w; b[4]=b1.x; b[5]=b1.y; b[6]=b1.z; b[7]=b1.w;

  float s[64];
  const float4* sv = (const float4*)(sw + (base + t * 8) * 8);
#pragma unroll
  for (int q = 0; q < 16; ++q) {
    float4 v = sv[q];
    s[q*4+0]=v.x; s[q*4+1]=v.y; s[q*4+2]=v.z; s[q*4+3]=v.w;
  }

  _Float16 tmp[72];
#pragma unroll
  for (int e = 0; e < 8; ++e) {
    tmp[e*9] = (_Float16)b[e];
#pragma unroll
    for (int g = 0; g < 8; ++g)
      tmp[e*9+1+g] = (_Float16)(0.1f * s[e*8+g]);
  }
  _Float16* d = buf + t * 72;            // t*144 bytes, 16B aligned
#pragma unroll
  for (int j = 0; j < 9; ++j)
    *(f16x8*)(d + j*8) = *(const f16x8*)(tmp + j*8);   // ds_write_b128
  __syncthreads();

  const f16x8* src = (const f16x8*)buf;
  f16x8* dst = (f16x8*)(W + base * 9);
#pragma unroll
  for (int c = 0; c < 9; ++c)
    dst[c * 256 + t] = src[c * 256 + t];               // coalesced 16B stores
}

// ---------------- prep: features, fp16, K-major [b][i*9+c] ----------------
__global__ __launch_bounds__(256) void prep_A(const float* __restrict__ x,
                                              const float* __restrict__ kn,
                                              _Float16* __restrict__ A) {
  __shared__ _Float16 buf[2048 * 9];
  const int t = threadIdx.x;
  const size_t base = (size_t)blockIdx.x * 2048;

  float k[8];
#pragma unroll
  for (int g = 0; g < 8; ++g) k[g] = kn[g];

  float v[8];
  const float4* xv = (const float4*)(x + base + t * 8);
  float4 v0 = xv[0], v1 = xv[1];
  v[0]=v0.x; v[1]=v0.y; v[2]=v0.z; v[3]=v0.w; v[4]=v1.x; v[5]=v1.y; v[6]=v1.z; v[7]=v1.w;

  _Float16 tmp[72];
#pragma unroll
  for (int e = 0; e < 8; ++e) {
    tmp[e*9] = (_Float16)v[e];
#pragma unroll
    for (int g = 0; g < 8; ++g) {
      float r = v[e] - k[g];
      tmp[e*9+1+g] = (_Float16)(r > 0.f ? r : 0.f);
    }
  }
  _Float16* d = buf + t * 72;
#pragma unroll
  for (int j = 0; j < 9; ++j)
    *(f16x8*)(d + j*8) = *(const f16x8*)(tmp + j*8);
  __syncthreads();

  const f16x8* src = (const f16x8*)buf;
  f16x8* dst = (f16x8*)(A + base * 9);
#pragma unroll
  for (int c = 0; c < 9; ++c)
    dst[c * 256 + t] = src[c * 256 + t];
}

// ---------------- GEMM: C[M,N] = A[M,K] @ W[N,K]^T, fp16 in / fp32 out ----------------
// XOR swizzle: physical 16B-chunk cp of row r holds logical chunk cp^(r&7).
// Staging keeps LDS dest = base + lane*16 (global_load_lds requirement);
// the permutation is applied to the per-lane GLOBAL source address.
#define BM 128
#define BN 128
#define BK 64

__global__ __launch_bounds__(256) void gemm_bt(const _Float16* __restrict__ A,
                                               const _Float16* __restrict__ W,
                                               float* __restrict__ C,
                                               int KC, size_t zstride) {
  constexpr int K = KDIM, N = OUT_F;
  __shared__ _Float16 As[BM * BK];   // 16 KB
  __shared__ _Float16 Bs[BN * BK];   // 16 KB

  const int tid  = threadIdx.x;
  const int lane = tid & 63;
  const int wv   = tid >> 6;
  const int wm   = wv >> 1;
  const int wn   = wv & 1;
  const int m0   = blockIdx.y * BM;
  const int n0   = blockIdx.x * BN;
  const int kBeg = blockIdx.z * KC;
  const int kEnd = kBeg + KC;
  float* Cd = C + (size_t)blockIdx.z * zstride;

  f32x4 acc[4][4] = {};

  // staging: 256 thr x 16B = 32 rows/pass, 4 passes. LDS dest = base + tid*16.
  const int rowS = tid >> 3;                                   // 0..31
  const int kgS  = ((tid & 7) ^ (rowS & 7)) * 8;               // swizzled global chunk

  for (int k0 = kBeg; k0 < kEnd; k0 += BK) {
#pragma unroll
    for (int p = 0; p < 4; ++p) {
      const int r = p * 32 + rowS;
      const _Float16* ga = A + (size_t)(m0 + r) * K + k0 + kgS;
      const _Float16* gw = W + (size_t)(n0 + r) * K + k0 + kgS;
      __builtin_amdgcn_global_load_lds(
          (const __attribute__((address_space(1))) void*)ga,
          (__attribute__((address_space(3))) void*)(As + r * BK + (tid & 7) * 8), 16, 0, 0);
      __builtin_amdgcn_global_load_lds(
          (const __attribute__((address_space(1))) void*)gw,
          (__attribute__((address_space(3))) void*)(Bs + r * BK + (tid & 7) * 8), 16, 0, 0);
    }
    __syncthreads();

#pragma unroll
    for (int kk = 0; kk < BK; kk += 32) {
      // logical chunk c = kk/8 + quad; physical = c ^ (r&7), r&7 == lane&7
      const int koff = (((kk >> 3) + (lane >> 4)) ^ (lane & 7)) * 8;
      f16x8 af[4], bfr[4];
#pragma unroll
      for (int mi = 0; mi < 4; ++mi) {
        const int r = wm * 64 + mi * 16 + (lane & 15);
        af[mi] = *(const f16x8*)(As + r * BK + koff);   // ds_read_b128, conflict-free
      }
#pragma unroll
      for (int ni = 0; ni < 4; ++ni) {
        const int r = wn * 64 + ni * 16 + (lane & 15);
        bfr[ni] = *(const f16x8*)(Bs + r * BK + koff);
      }
#pragma unroll
      for (int mi = 0; mi < 4; ++mi)
#pragma unroll
        for (int ni = 0; ni < 4; ++ni)
          acc[mi][ni] = __builtin_amdgcn_mfma_f32_16x16x32_f16(af[mi], bfr[ni],
                                                               acc[mi][ni], 0, 0, 0);
    }
    __syncthreads();
  }

  // C/D layout: col=lane&15, row=(lane>>4)*4+reg
  const int cn = lane & 15;
  const int r4 = (lane >> 4) * 4;
#pragma unroll
  for (int mi = 0; mi < 4; ++mi) {
    const int rowb = m0 + wm * 64 + mi * 16 + r4;
#pragma unroll
    for (int ni = 0; ni < 4; ++ni) {
      const int col = n0 + wn * 64 + ni * 16 + cn;
#pragma unroll
      for (int reg = 0; reg < 4; ++reg)
        Cd[(size_t)(rowb + reg) * N + col] = acc[mi][ni][reg];
    }
  }
}

// ---------------- split-K reduce ----------------
template <int S>
__global__ __launch_bounds__(256) void reduceK(const float* __restrict__ part,
                                               float* __restrict__ out) {
  const size_t i = ((size_t)blockIdx.x * 256 + threadIdx.x) * 4;
  f32x4 a = *(const f32x4*)(part + i);
#pragma unroll
  for (int s = 1; s < S; ++s)
    a += *(const f32x4*)(part + (size_t)s * MN + i);
  *(f32x4*)(out + i) = a;
}

// ---------------- fallback: fp32, wave per (b,o) ----------------
__global__ __launch_bounds__(256) void kan_naive(const float* __restrict__ x,
                                                 const float* __restrict__ bw,
                                                 const float* __restrict__ sw,
                                                 const float* __restrict__ kn,
                                                 float* __restrict__ out) {
  const int lane = threadIdx.x & 63;
  const int o = blockIdx.x * 4 + (threadIdx.x >> 6);
  const int b = blockIdx.y;
  float k[8];
#pragma unroll
  for (int g = 0; g < 8; ++g) k[g] = kn[g];
  float acc = 0.f;
  for (int i = lane; i < IN_F; i += 64) {
    const float v = x[(size_t)b * IN_F + i];
    float sp = 0.f;
    const float* s = sw + ((size_t)o * IN_F + i) * 8;
#pragma unroll
    for (int g = 0; g < 8; ++g) {
      float r = v - k[g];
      sp += s[g] * (r > 0.f ? r : 0.f);
    }
    acc += v * bw[(size_t)o * IN_F + i] + 0.1f * sp;
  }
#pragma unroll
  for (int off = 32; off; off >>= 1) acc += __shfl_down(acc, off, 64);
  if (lane == 0) out[(size_t)b * OUT_F + o] = acc;
}

extern "C" void kernel_launch(void* const* d_in, const int* in_sizes, int n_in,
                              void* d_out, int out_size, void* d_ws, size_t ws_size,
                              hipStream_t stream) {
  const float* x  = (const float*)d_in[0];
  const float* bw = (const float*)d_in[1];
  const float* sw = (const float*)d_in[2];
  const float* kn = (const float*)d_in[3];
  float* out = (float*)d_out;

  const size_t wbytes = (size_t)OUT_F * KDIM * sizeof(_Float16);   // 72 MB
  const size_t abytes = (size_t)BATCH * KDIM * sizeof(_Float16);   // 144 MB
  const size_t pbytes = MN * sizeof(float);                        // 32 MB per split

  if (ws_size < wbytes + abytes) {
    dim3 grid(OUT_F / 4, BATCH);
    kan_naive<<<grid, 256, 0, stream>>>(x, bw, sw, kn, out);
    return;
  }

  _Float16* W = (_Float16*)d_ws;
  _Float16* A = (_Float16*)((char*)d_ws + wbytes);
  float* part  = (float*)((char*)d_ws + wbytes + abytes);

  prep_W<<<(OUT_F * IN_F) / 2048, 256, 0, stream>>>(bw, sw, W);
  prep_A<<<(BATCH * IN_F) / 2048, 256, 0, stream>>>(x, kn, A);

  int S = 1;
  if (ws_size >= wbytes + abytes + 4 * pbytes)      S = 4;
  else if (ws_size >= wbytes + abytes + 2 * pbytes) S = 2;

  dim3 grid(OUT_F / BN, BATCH / BM, S);             // 512*S blocks
  if (S == 1) {
    gemm_bt<<<grid, 256, 0, stream>>>(A, W, out, KDIM, 0);
  } else {
    gemm_bt<<<grid, 256, 0, stream>>>(A, W, part, KDIM / S, MN);
  }
  if (S == 2) reduceK<2><<<MN / 1024, 256, 0, stream>>>(part, out);
  if (S == 4) reduceK<4><<<MN / 1024, 256, 0, stream>>>(part, out);
}